// Round 1
// 309.697 us; speedup vs baseline: 1.1692x; 1.1692x over previous
//
#include <hip/hip_runtime.h>
#include <stdint.h>

// ---------------- problem constants ----------------
#define GN   33
#define GG   1089      // 33*33
#define GGG  35937     // 33^3
#define BATCH 4
#define HFULL 1080
#define WFULL 1920
#define NPIX (HFULL*WFULL)          // 2,073,600 per channel
#define NPIX4 (NPIX/4)              // 518,400 float4 per channel

// d_out layout (floats): out | alpha | delta | L | delta_norm
#define OUT_ALPHA 24883200
#define OUT_DELTA 24883232
#define OUT_L     25314476
#define OUT_DNORM 25745720

// ---------------- workspace layout ----------------
// bytes [0, 9,199,872): 64B-entry packed LUT (4*35937 entries)
#define WS_LUT64B 0
#define WS_PART   2300000   // encoder partials [enc2][b4][tile32][o32]
#define WS_DN     2308192   // 132 per-block |delta| partials
#define NLUTBLK   132       // 4 batches * 33 x-planes

// native clang vectors (required by __builtin_nontemporal_*)
typedef float  float4n __attribute__((ext_vector_type(4)));
typedef unsigned int uint4n __attribute__((ext_vector_type(4)));

__device__ __forceinline__ unsigned short f2bf(float f) {
    unsigned u = __float_as_uint(f);
    unsigned r = (u + 0x7fffu + ((u >> 16) & 1u)) >> 16;
    return (unsigned short)r;
}
__device__ __forceinline__ float bflo(unsigned u) { return __uint_as_float(u << 16); }
__device__ __forceinline__ float bfhi(unsigned u) { return __uint_as_float(u & 0xffff0000u); }

// ---------------- fused encoder: conv1(3->16,s2) + conv2(16->32,s2) + mean partials ----------------
__global__ __launch_bounds__(256) void encoder_kernel(
    const float* __restrict__ img,
    const float* __restrict__ w1wp, const float* __restrict__ b1wp,
    const float* __restrict__ w2wp, const float* __restrict__ b2wp,
    const float* __restrict__ w1rp, const float* __restrict__ b1rp,
    const float* __restrict__ w2rp, const float* __restrict__ b2rp,
    float* __restrict__ ws)
{
    const int bi = blockIdx.x;
    const int enc = bi >> 7, b = (bi >> 5) & 3, rt = (bi >> 1) & 15, ct = bi & 1;
    const float* w1 = enc ? w1rp : w1wp;
    const float* b1 = enc ? b1rp : b1wp;
    const float* w2 = enc ? w2rp : w2wp;
    const float* b2 = enc ? b2rp : b2wp;
    __shared__ float simg[3][19][132];
    __shared__ float sh1[4][9][66];
    __shared__ float red[4][16];
    const float* imb = img + (size_t)b * 3 * 65536;
    const int tid = threadIdx.x;

    for (int l = tid; l < 3 * 19 * 131; l += 256) {
        const int c = l / (19 * 131);
        const int rem = l - c * (19 * 131);
        const int rw = rem / 131, cl = rem - rw * 131;
        const int gr = 16 * rt - 3 + rw, gc = 128 * ct - 3 + cl;
        float v = 0.f;
        if ((unsigned)gr < 256u && (unsigned)gc < 256u)
            v = imb[(c << 16) + (gr << 8) + gc];
        simg[c][rw][cl] = v;
    }
    __syncthreads();

    const int p = tid & 127, h = tid >> 7;
    const int prow = p >> 5, pcol = p & 31;
    float acc[16];
    #pragma unroll
    for (int o = 0; o < 16; ++o) acc[o] = b2[h * 16 + o];

    for (int cc0 = 0; cc0 < 16; cc0 += 4) {
        if (cc0) __syncthreads();
        for (int l = tid; l < 4 * 9 * 65; l += 256) {
            const int oc = l / (9 * 65);
            const int rem = l - oc * (9 * 65);
            const int r = rem / 65, cl = rem - r * 65;
            const int hrow = 8 * rt - 1 + r, hcol = 64 * ct - 1 + cl;
            float v = 0.f;
            if ((unsigned)hrow < 128u && (unsigned)hcol < 128u) {
                float a1 = b1[cc0 + oc];
                const float* wo = w1 + (cc0 + oc) * 27;
                #pragma unroll
                for (int c = 0; c < 3; ++c)
                    #pragma unroll
                    for (int ky = 0; ky < 3; ++ky)
                        #pragma unroll
                        for (int kx = 0; kx < 3; ++kx)
                            a1 += wo[c * 9 + ky * 3 + kx] * simg[c][2 * r + ky][2 * cl + kx];
                v = fmaxf(a1, 0.f);
            }
            sh1[oc][r][cl] = v;
        }
        __syncthreads();
        #pragma unroll
        for (int cc = 0; cc < 4; ++cc) {
            float vv[9];
            #pragma unroll
            for (int ky = 0; ky < 3; ++ky)
                #pragma unroll
                for (int kx = 0; kx < 3; ++kx)
                    vv[ky * 3 + kx] = sh1[cc][2 * prow + ky][2 * pcol + kx];
            #pragma unroll
            for (int o = 0; o < 16; ++o) {
                const float* wo = w2 + (h * 16 + o) * 144 + (cc0 + cc) * 9;
                #pragma unroll
                for (int k = 0; k < 9; ++k) acc[o] += wo[k] * vv[k];
            }
        }
    }
    const int lane = tid & 63, wv = tid >> 6;
    #pragma unroll
    for (int o = 0; o < 16; ++o) {
        float v = fmaxf(acc[o], 0.f);
        #pragma unroll
        for (int off = 32; off; off >>= 1) v += __shfl_down(v, off);
        if (lane == 0) red[wv][o] = v;
    }
    __syncthreads();
    if (tid < 32) {
        const int o = tid & 15, g = tid >> 4;
        const float s = red[g * 2][o] + red[g * 2 + 1][o];
        ws[WS_PART + ((enc * 4 + b) * 32 + (rt * 2 + ct)) * 32 + g * 16 + o] = s;
    }
}

// ---------------- fused heads + plane-pair LUT build + pack ----------------
// block = (b, x-plane). Computes planes x and x+1 ONCE each into LDS
// (2x total redundancy vs 8x per-corner recompute), then packs plane x.
__global__ __launch_bounds__(256) void lut_kernel(
    const float* __restrict__ bases,
    const float* __restrict__ wp_fc_w, const float* __restrict__ wp_fc_b,
    const float* __restrict__ fcu_w, const float* __restrict__ fcu_b,
    const float* __restrict__ fcv_w, const float* __restrict__ fcv_b,
    const float* __restrict__ fcw_w, const float* __restrict__ fcw_b,
    const float* __restrict__ fcc_w, const float* __restrict__ fcc_b,
    float* __restrict__ ws, float* __restrict__ dout)
{
    const int b = blockIdx.x & 3;
    const int x = blockIdx.x >> 2;          // 0..32
    const int x1 = min(x + 1, GN - 1);
    const int tid = threadIdx.x;
    __shared__ float mean[2][32];
    __shared__ float U[264], V[264], W[264], Cc[24], Al[8];
    __shared__ float Lp[2][GG * 3];         // 26.1 KB: L for planes x, x1

    // phase 1a: reduce encoder partials
    if (tid < 64) {
        const int enc = tid >> 5, o = tid & 31;
        const float* pp = ws + WS_PART + (enc * 4 + b) * 1024 + o;
        float s = 0.f;
        #pragma unroll
        for (int i = 0; i < 32; ++i) s += pp[i * 32];
        mean[enc][o] = s * (1.f / 4096.f);
    }
    __syncthreads();
    // phase 1b: FC heads (redundant per block, trivial)
    for (int r = tid; r < 824; r += 256) {
        if (r < 8) {
            const float* row = wp_fc_w + r * 32;
            float a = wp_fc_b[r];
            #pragma unroll 8
            for (int q = 0; q < 32; ++q) a += row[q] * mean[0][q];
            Al[r] = a;
            dout[OUT_ALPHA + b * 8 + r] = a;
        } else if (r < 272) {
            const int jj = r - 8;
            const float* row = fcu_w + jj * 32;
            float a = fcu_b[jj];
            #pragma unroll 8
            for (int q = 0; q < 32; ++q) a += row[q] * mean[1][q];
            U[jj] = a;
        } else if (r < 536) {
            const int jj = r - 272;
            const float* row = fcv_w + jj * 32;
            float a = fcv_b[jj];
            #pragma unroll 8
            for (int q = 0; q < 32; ++q) a += row[q] * mean[1][q];
            V[jj] = a;
        } else if (r < 800) {
            const int jj = r - 536;
            const float* row = fcw_w + jj * 32;
            float a = fcw_b[jj];
            #pragma unroll 8
            for (int q = 0; q < 32; ++q) a += row[q] * mean[1][q];
            W[jj] = a;
        } else {
            const int jj = r - 800;
            const float* row = fcc_w + jj * 32;
            float a = fcc_b[jj];
            #pragma unroll 8
            for (int q = 0; q < 32; ++q) a += row[q] * mean[1][q];
            Cc[jj] = a;
        }
    }
    __syncthreads();

    float ux0[8], ux1[8], cr[8][3];
    #pragma unroll
    for (int r = 0; r < 8; ++r) {
        ux0[r] = U[r * GN + x];
        ux1[r] = U[r * GN + x1];
        cr[r][0] = Cc[r * 3 + 0];
        cr[r][1] = Cc[r * 3 + 1];
        cr[r][2] = Cc[r * 3 + 2];
    }

    // phase 2: compute L for both planes, coalesced bases reads
    float sum3 = 0.f;
    #pragma unroll
    for (int px = 0; px < 2; ++px) {
        const int xi = px ? x1 : x;
        for (int i = tid; i < GG; i += 256) {
            const int y = i / GN, z = i - y * GN;
            float d0 = 0.f, d1 = 0.f, d2 = 0.f;
            #pragma unroll
            for (int r = 0; r < 8; ++r) {
                const float t = (px ? ux1[r] : ux0[r]) * V[r * GN + y] * W[r * GN + z];
                d0 += t * cr[r][0];
                d1 += t * cr[r][1];
                d2 += t * cr[r][2];
            }
            float l0 = d0, l1 = d1, l2 = d2;
            const float* bp = bases + (size_t)(xi * GG + i) * 3;
            #pragma unroll
            for (int k = 0; k < 8; ++k) {
                const float a = Al[k];
                const float* bk = bp + (size_t)k * GGG * 3;
                l0 += a * bk[0];
                l1 += a * bk[1];
                l2 += a * bk[2];
            }
            Lp[px][i * 3 + 0] = l0;
            Lp[px][i * 3 + 1] = l1;
            Lp[px][i * 3 + 2] = l2;
            if (px == 0) {
                const size_t o3 = ((size_t)b * GGG + x * GG + i) * 3;
                dout[OUT_DELTA + o3 + 0] = d0;
                dout[OUT_DELTA + o3 + 1] = d1;
                dout[OUT_DELTA + o3 + 2] = d2;
                dout[OUT_L + o3 + 0] = l0;
                dout[OUT_L + o3 + 1] = l1;
                dout[OUT_L + o3 + 2] = l2;
                sum3 += fabsf(d0) + fabsf(d1) + fabsf(d2);
            }
        }
    }
    __syncthreads();

    // phase 3: pack entries for plane x from LDS
    for (int i = tid; i < GG; i += 256) {
        const int y = i / GN, z = i - y * GN;
        const int y1 = min(y + 1, GN - 1), z1 = min(z + 1, GN - 1);
        const int i00 = (y  * GN + z ) * 3, i01 = (y  * GN + z1) * 3;
        const int i10 = (y1 * GN + z ) * 3, i11 = (y1 * GN + z1) * 3;
        uint4 wr, wg, wb;
        #pragma unroll
        for (int c = 0; c < 3; ++c) {
            const unsigned w00 = (unsigned)f2bf(Lp[0][i00 + c]) | ((unsigned)f2bf(Lp[0][i01 + c]) << 16);
            const unsigned w01 = (unsigned)f2bf(Lp[0][i10 + c]) | ((unsigned)f2bf(Lp[0][i11 + c]) << 16);
            const unsigned w10 = (unsigned)f2bf(Lp[1][i00 + c]) | ((unsigned)f2bf(Lp[1][i01 + c]) << 16);
            const unsigned w11 = (unsigned)f2bf(Lp[1][i10 + c]) | ((unsigned)f2bf(Lp[1][i11 + c]) << 16);
            uint4& wv = c == 0 ? wr : (c == 1 ? wg : wb);
            wv.x = w00; wv.y = w01; wv.z = w10; wv.w = w11;
        }
        uint4* dst = (uint4*)((char*)ws + WS_LUT64B) + ((size_t)b * GGG + x * GG + i) * 4;
        dst[0] = wr; dst[1] = wg; dst[2] = wb;
    }

    // per-block |delta| partial
    #pragma unroll
    for (int off = 32; off; off >>= 1) sum3 += __shfl_down(sum3, off);
    __shared__ float s4[4];
    const int lane = tid & 63, wid = tid >> 6;
    if (!lane) s4[wid] = sum3;
    __syncthreads();
    if (!tid) ws[WS_DN + blockIdx.x] = s4[0] + s4[1] + s4[2] + s4[3];
}

// ---------------- trilinear apply (+ dnorm finish in block 0) ----------------
// Quad-cooperative LUT gather: each quad of lanes fetches one pixel's 64 B
// entry with 4 consecutive dwordx4 lanes (1 cache line / pixel / instruction,
// 16 lines per wave-instruction instead of 64). Lane j of the quad computes
// channel j's trilerp (entry layout is one uint4 per channel; lane 3 rides on
// the pad and is predicated off). (idx,xd,yd,zd) broadcast within the quad via
// width-4 __shfl (DPP quad_perm). Results transposed back to coalesced
// per-channel float4 layout through a swizzled LDS buffer (stride-17 write
// pattern -> conflict-free).
__global__ __launch_bounds__(256, 4) void apply_kernel(
    const float* __restrict__ img,
    const float* __restrict__ ws, float* __restrict__ dout)
{
    __shared__ float so[3 * 1093];   // [c][p + (p>>4)] swizzled, p in [0,1024)

    if (blockIdx.x == 0 && threadIdx.x < 64) {
        float s = 0.f;
        for (int i = threadIdx.x; i < NLUTBLK; i += 64) s += ws[WS_DN + i];
        #pragma unroll
        for (int off = 32; off; off >>= 1) s += __shfl_down(s, off);
        if (threadIdx.x == 0)
            dout[OUT_DNORM] = s * (1.0f / (float)(BATCH * GGG * 3));
    }
    const int b = blockIdx.x & 3;     // with round-robin block->XCD, XCD j sees only batch j&3
    const int tid = threadIdx.x;
    const int q = (blockIdx.x >> 2) * 256 + tid;
    const float4n* base = (const float4n*)(img + (size_t)b * 3 * NPIX);
    const float4n rv = __builtin_nontemporal_load(&base[q]);
    const float4n gv = __builtin_nontemporal_load(&base[NPIX4 + q]);
    const float4n bv = __builtin_nontemporal_load(&base[2 * NPIX4 + q]);
    const uint4* lut = (const uint4*)((const char*)ws + WS_LUT64B) + (size_t)b * GGG * 4;

    float rrr[4] = {rv.x, rv.y, rv.z, rv.w};
    float ggg[4] = {gv.x, gv.y, gv.z, gv.w};
    float bbb[4] = {bv.x, bv.y, bv.z, bv.w};
    int idx[4]; float xd[4], yd[4], zd[4];
    #pragma unroll
    for (int t = 0; t < 4; ++t) {
        const float xf = fminf(fmaxf(rrr[t] * 32.f, 0.f), 31.999998f);
        const float yf = fminf(fmaxf(ggg[t] * 32.f, 0.f), 31.999998f);
        const float zf = fminf(fmaxf(bbb[t] * 32.f, 0.f), 31.999998f);
        const int x0 = (int)xf, y0 = (int)yf, z0 = (int)zf;
        xd[t] = xf - (float)x0; yd[t] = yf - (float)y0; zd[t] = zf - (float)z0;
        idx[t] = (x0 * GN + y0) * GN + z0;
    }

    const int sub = tid & 3;          // lane within quad == channel (3 = pad)
    const int qd  = tid >> 2;         // quad index within block
    // 16 rounds: round r handles the pixel at slot (r&3) of quad-owner sub-lane (r>>2)
    #pragma unroll
    for (int r = 0; r < 16; ++r) {
        const int src = r >> 2, sl = r & 3;
        const int   pidx = __shfl(idx[sl], src, 4);
        const float pxd  = __shfl(xd[sl],  src, 4);
        const float pyd  = __shfl(yd[sl],  src, 4);
        const float pzd  = __shfl(zd[sl],  src, 4);
        const uint4 e = lut[(size_t)(unsigned)pidx * 4 + sub];
        const float e0l = bflo(e.x), e1l = bflo(e.y), e2l = bflo(e.z), e3l = bflo(e.w);
        const float z00 = e0l + pzd * (bfhi(e.x) - e0l);
        const float z01 = e1l + pzd * (bfhi(e.y) - e1l);
        const float z10 = e2l + pzd * (bfhi(e.z) - e2l);
        const float z11 = e3l + pzd * (bfhi(e.w) - e3l);
        const float y0v = z00 + pyd * (z01 - z00);
        const float y1v = z10 + pyd * (z11 - z10);
        const float ov  = y0v + pxd * (y1v - y0v);
        // local pixel index p = qd*16 + r; swizzled addr = p + (p>>4) = qd*17 + r
        if (sub < 3) so[sub * 1093 + qd * 17 + r] = ov;
    }
    __syncthreads();

    // readback: channel c, pixels 4*tid .. 4*tid+3 -> addr = c*1093 + 4*tid + (tid>>2) + j
    const int pb = 4 * tid + qd;
    float4n s0, s1, s2;
    s0.x = so[pb + 0];        s0.y = so[pb + 1];        s0.z = so[pb + 2];        s0.w = so[pb + 3];
    s1.x = so[1093 + pb + 0]; s1.y = so[1093 + pb + 1]; s1.z = so[1093 + pb + 2]; s1.w = so[1093 + pb + 3];
    s2.x = so[2186 + pb + 0]; s2.y = so[2186 + pb + 1]; s2.z = so[2186 + pb + 2]; s2.w = so[2186 + pb + 3];

    float4n* ob = (float4n*)(dout + (size_t)b * 3 * NPIX);
    __builtin_nontemporal_store(s0, &ob[q]);
    __builtin_nontemporal_store(s1, &ob[NPIX4 + q]);
    __builtin_nontemporal_store(s2, &ob[2 * NPIX4 + q]);
}

extern "C" void kernel_launch(void* const* d_in, const int* in_sizes, int n_in,
                              void* d_out, int out_size, void* d_ws, size_t ws_size,
                              hipStream_t stream)
{
    const float* img_lr   = (const float*)d_in[0];
    const float* img_full = (const float*)d_in[1];
    const float* bases    = (const float*)d_in[2];
    const float* wp_c1_w  = (const float*)d_in[3];
    const float* wp_c1_b  = (const float*)d_in[4];
    const float* wp_c2_w  = (const float*)d_in[5];
    const float* wp_c2_b  = (const float*)d_in[6];
    const float* wp_fc_w  = (const float*)d_in[7];
    const float* wp_fc_b  = (const float*)d_in[8];
    const float* rp_c1_w  = (const float*)d_in[9];
    const float* rp_c1_b  = (const float*)d_in[10];
    const float* rp_c2_w  = (const float*)d_in[11];
    const float* rp_c2_b  = (const float*)d_in[12];
    const float* fcu_w    = (const float*)d_in[13];
    const float* fcu_b    = (const float*)d_in[14];
    const float* fcv_w    = (const float*)d_in[15];
    const float* fcv_b    = (const float*)d_in[16];
    const float* fcw_w    = (const float*)d_in[17];
    const float* fcw_b    = (const float*)d_in[18];
    const float* fcc_w    = (const float*)d_in[19];
    const float* fcc_b    = (const float*)d_in[20];
    float* ws  = (float*)d_ws;
    float* out = (float*)d_out;

    encoder_kernel<<<dim3(256), 256, 0, stream>>>(
        img_lr, wp_c1_w, wp_c1_b, wp_c2_w, wp_c2_b,
        rp_c1_w, rp_c1_b, rp_c2_w, rp_c2_b, ws);
    lut_kernel<<<dim3(NLUTBLK), 256, 0, stream>>>(
        bases, wp_fc_w, wp_fc_b, fcu_w, fcu_b, fcv_w, fcv_b,
        fcw_w, fcw_b, fcc_w, fcc_b, ws, out);
    apply_kernel<<<dim3(BATCH * NPIX4 / 256), 256, 0, stream>>>(img_full, ws, out);
}